// Round 5
// baseline (489.899 us; speedup 1.0000x reference)
//
#include <hip/hip_runtime.h>
#include <hip/hip_fp16.h>
#include <stdint.h>

#define IN    4096
#define OUT   4096
#define BATCH 8192
#define TK    64
#define BT    8     // batch rows per block in the spmm kernel

typedef float  fx4 __attribute__((ext_vector_type(4)));   // native vector for nt-load

// ---------------------------------------------------------------------------
// Kernel 1: ONE WAVE PER ROW top-K.
//  - 16-round MSB-greedy threshold search on the TOP 16 BITS of the
//    order-preserving key transform (key>>16 >= P  <=>  key >= P<<16).
//  - exact tie resolution inside the 16-bit boundary bucket (expected 1-3
//    members, guarded to 128) via 28-round ballot search over
//    packed = (low16<<12) | (4095-idx); inverted idx prefers SMALLER index,
//    matching jax.lax.top_k tie order.
//  - emission positions bank-quad scheduled: pos k gets idx with
//    idx&7 == (row+k)&7 where possible (spmm step-k gather spreads 64 lanes
//    over the 8 LDS bank quads).
//  - wt payload: {idx, fp16(val) duplicated in both halves} feeding
//    v_pk_fma_f16 in spmm with zero conversion.
// ---------------------------------------------------------------------------
__global__ __launch_bounds__(256)
void topk_build_kernel(const float* __restrict__ pre_w,
                       const float* __restrict__ sign_m,
                       int2* __restrict__ wt) {
  __shared__ int selbuf[4][TK];
  __shared__ uint32_t bucket[4][128];

  const int wid  = threadIdx.x >> 6;
  const int lane = threadIdx.x & 63;
  const int row  = blockIdx.x * 4 + wid;
  const float* pw = pre_w + (size_t)row * IN;
  const uint64_t lt = (1ull << lane) - 1ull;

  // load 64 keys per lane; keys[j*4+c] <-> global index j*256 + lane*4 + c
  uint32_t keys[64];
  #pragma unroll
  for (int j = 0; j < 16; ++j) {
    const float4 v = *(const float4*)(pw + j * 256 + lane * 4);
    const uint32_t u0 = __float_as_uint(v.x);
    const uint32_t u1 = __float_as_uint(v.y);
    const uint32_t u2 = __float_as_uint(v.z);
    const uint32_t u3 = __float_as_uint(v.w);
    keys[j * 4 + 0] = (u0 & 0x80000000u) ? ~u0 : (u0 | 0x80000000u);
    keys[j * 4 + 1] = (u1 & 0x80000000u) ? ~u1 : (u1 | 0x80000000u);
    keys[j * 4 + 2] = (u2 & 0x80000000u) ? ~u2 : (u2 | 0x80000000u);
    keys[j * 4 + 3] = (u3 & 0x80000000u) ? ~u3 : (u3 | 0x80000000u);
  }

  // ---- phase A: largest 16-bit prefix P with count(key>>16 >= P) >= TK ----
  uint32_t curH = 0u;
  for (int b = 15; b >= 0; --b) {
    const uint32_t candF = (curH | (1u << b)) << 16;
    int c = 0;
    #pragma unroll
    for (int i = 0; i < 64; ++i) c += (keys[i] >= candF) ? 1 : 0;
    #pragma unroll
    for (int off = 32; off > 0; off >>= 1) c += __shfl_xor(c, off, 64);
    if (c >= TK) curH |= (1u << b);
  }

  // strict-above count ng and bucket count nb (packed 16|16 single reduce)
  int pk = 0;
  #pragma unroll
  for (int i = 0; i < 64; ++i) {
    const uint32_t kh = keys[i] >> 16;
    pk += (kh > curH) ? 1 : 0;
    pk += (kh == curH) ? (1 << 16) : 0;
  }
  #pragma unroll
  for (int off = 32; off > 0; off >>= 1) pk += __shfl_xor(pk, off, 64);
  const int ng = pk & 0xFFFF;
  const int nb = pk >> 16;
  const int m  = TK - ng;            // 1..TK entries to take from the bucket

  // ---- phase B: collect bucket, find m-th largest packed value ----
  {
    int base = 0;
    #pragma unroll
    for (int i = 0; i < 64; ++i) {
      const bool hit = (keys[i] >> 16) == curH;
      const uint64_t msk = __ballot(hit);
      if (hit) {
        const int p = base + (int)__popcll(msk & lt);
        const int idx = (i >> 2) * 256 + lane * 4 + (i & 3);
        if (p < 128) bucket[wid][p] = ((keys[i] & 0xFFFFu) << 12) | (uint32_t)(4095 - idx);
      }
      base += (int)__popcll(msk);
    }
  }
  __syncthreads();

  const uint32_t v0 = (lane      < nb) ? bucket[wid][lane]      : 0u;
  const uint32_t v1 = (lane + 64 < nb) ? bucket[wid][lane + 64] : 0u;
  uint32_t curB = 0u;
  for (int b = 27; b >= 0; --b) {
    const uint32_t cand = curB | (1u << b);
    const int c = (int)__popcll(__ballot(v0 >= cand)) + (int)__popcll(__ballot(v1 >= cand));
    if (c >= m) curB = cand;
  }

  // ---- emission: compact the exact selection set into selbuf ----
  {
    int base = 0;
    #pragma unroll
    for (int i = 0; i < 64; ++i) {
      const uint32_t kh = keys[i] >> 16;
      const int idx = (i >> 2) * 256 + lane * 4 + (i & 3);
      const uint32_t packed = ((keys[i] & 0xFFFFu) << 12) | (uint32_t)(4095 - idx);
      const bool sel = (kh > curH) || ((kh == curH) && (packed >= curB));
      const uint64_t msk = __ballot(sel);
      if (sel) selbuf[wid][base + (int)__popcll(msk & lt)] = idx;
      base += (int)__popcll(msk);
    }
  }
  __syncthreads();

  // ---- bank-quad position assignment (ballot-based, rotated levels) ----
  const int myidx = selbuf[wid][lane];   // exactly TK=64 entries = 64 lanes
  const int q = myidx & 7;               // LDS bank quad of this index
  const int s = (row >> 3) & 7;          // per-row level rotation

  uint64_t mymask = 0ull;
  int cq[8];
  #pragma unroll
  for (int j = 0; j < 8; ++j) {
    const uint64_t mm = __ballot(q == j);
    cq[j] = (int)__popcll(mm);
    if (q == j) mymask = mm;
  }
  const int r = (int)__popcll(mymask & lt);  // rank within quad class

  int pos;
  if (r < 8) {
    pos = ((q - row) & 7) + 8 * ((r + s) & 7);
  } else {
    int R = r - 8;
    #pragma unroll
    for (int j = 0; j < 8; ++j) if (j < q && cq[j] > 8) R += cq[j] - 8;
    int acc = 0; pos = -1;
    #pragma unroll
    for (int cc = 0; cc < 8; ++cc) {
      int g = 0;
      #pragma unroll
      for (int j = 0; j < 8; ++j)
        if (((row + cc) & 7) == j) g = (cq[j] < 8) ? cq[j] : 8;
      const int f = 8 - g;
      if (pos < 0 && R < acc + f) pos = cc + 8 * ((g + (R - acc) + s) & 7);
      acc += f;
    }
  }

  const float v = expf(pw[myidx]) * sign_m[(size_t)row * IN + myidx];
  const uint32_t hb = (uint32_t)__half_as_ushort(__float2half_rn(v));
  int2* dst = wt + (((size_t)(pos >> 1) * OUT + row) * 2 + (pos & 1));
  *dst = make_int2(myidx, (int)(hb | (hb << 16)));
}

// ---------------------------------------------------------------------------
// Kernel 2: sparse matmul. Block = BT batch rows x all OUT outputs.
// x staged in LDS fp16 transposed (row i = 8 batch vals = 16 B).
// Per (o,k): 1x ds_read_b128 gather + 4x v_pk_fma_f16. fp16 accumulation in
// 4 independent chains of length 16 (STATIC indexing only), combined in fp32.
// x loads / out stores are non-temporal: both touched exactly once, keep
// them out of the L2 that serves ~2 GB of wt re-reads.
// ---------------------------------------------------------------------------
__device__ __forceinline__ uint32_t pack_f16x2(float a, float b) {
  const uint32_t lo = __half_as_ushort(__float2half(a));
  const uint32_t hi = __half_as_ushort(__float2half(b));
  return lo | (hi << 16);
}

__global__ __launch_bounds__(1024, 8)
void spmm_topk_kernel(const float* __restrict__ x,
                      const int4* __restrict__ wt4,
                      float* __restrict__ out) {
  __shared__ uint16_t ldsx[IN * BT];   // 64 KB: row i at byte offset i*16

  const int tid = threadIdx.x;
  const int b0 = blockIdx.x * BT;

  // ---- stage: 8 rows of x -> LDS fp16 transposed ----
  {
    const int i4 = tid * 4;
    float c[4][BT];
    #pragma unroll
    for (int j = 0; j < BT; ++j) {
      const fx4* src = (const fx4*)(x + (size_t)(b0 + j) * IN + i4);
      const fx4 v = __builtin_nontemporal_load(src);
      c[0][j] = v.x; c[1][j] = v.y; c[2][j] = v.z; c[3][j] = v.w;
    }
    #pragma unroll
    for (int rr = 0; rr < 4; ++rr) {
      uint4 pkv;
      pkv.x = pack_f16x2(c[rr][0], c[rr][1]);
      pkv.y = pack_f16x2(c[rr][2], c[rr][3]);
      pkv.z = pack_f16x2(c[rr][4], c[rr][5]);
      pkv.w = pack_f16x2(c[rr][6], c[rr][7]);
      *(uint4*)(&ldsx[(i4 + rr) * BT]) = pkv;
    }
  }
  __syncthreads();

  const int wave = tid >> 6;
  const int lane = tid & 63;

  for (int g = wave; g < (OUT / 64); g += 16) {   // 4 groups per wave
    const int o = g * 64 + lane;
    const int4* wq = wt4 + o;                     // element k2 at wq[k2*OUT]

    __half2 acc0[4], acc1[4], acc2[4], acc3[4];   // 4 chains x 4 batch-pairs
    #pragma unroll
    for (int j = 0; j < 4; ++j) {
      acc0[j] = __float2half2_rn(0.f);
      acc1[j] = __float2half2_rn(0.f);
      acc2[j] = __float2half2_rn(0.f);
      acc3[j] = __float2half2_rn(0.f);
    }

    for (int k8 = 0; k8 < TK / 8; ++k8) {         // 8 k-entries per iter
      #pragma unroll
      for (int c = 0; c < 4; ++c) {               // chain c gets k2 = k8*4+c
        const int4 p = wq[(size_t)(k8 * 4 + c) * OUT];       // {idx0,dup0,idx1,dup1}
        const uint4 xa = *(const uint4*)(&ldsx[p.x * BT]);   // quad-scheduled gather
        const uint4 xb = *(const uint4*)(&ldsx[p.z * BT]);
        const __half2 va = *(const __half2*)&p.y;
        const __half2 vb = *(const __half2*)&p.w;
        const __half2* ha = (const __half2*)&xa;
        const __half2* hb = (const __half2*)&xb;
        __half2* ac = (c == 0) ? acc0 : (c == 1) ? acc1 : (c == 2) ? acc2 : acc3;
        #pragma unroll
        for (int j = 0; j < 4; ++j) {
          ac[j] = __hfma2(ha[j], va, ac[j]);
          ac[j] = __hfma2(hb[j], vb, ac[j]);
        }
      }
    }

    // epilogue: combine 4 fp16 chains in fp32, non-temporal store
    float* op = out + (size_t)b0 * OUT + o;
    #pragma unroll
    for (int j = 0; j < 4; ++j) {
      const float lo = (__low2float(acc0[j])  + __low2float(acc1[j])) +
                       (__low2float(acc2[j])  + __low2float(acc3[j]));
      const float hi = (__high2float(acc0[j]) + __high2float(acc1[j])) +
                       (__high2float(acc2[j]) + __high2float(acc3[j]));
      __builtin_nontemporal_store(lo, op + (size_t)(2 * j) * OUT);
      __builtin_nontemporal_store(hi, op + (size_t)(2 * j + 1) * OUT);
    }
  }
}

// ---------------------------------------------------------------------------
extern "C" void kernel_launch(void* const* d_in, const int* in_sizes, int n_in,
                              void* d_out, int out_size, void* d_ws, size_t ws_size,
                              hipStream_t stream) {
  const float* x      = (const float*)d_in[0];
  const float* pre_w  = (const float*)d_in[1];
  const float* sign_m = (const float*)d_in[2];
  float* out = (float*)d_out;

  topk_build_kernel<<<OUT / 4, 256, 0, stream>>>(pre_w, sign_m, (int2*)d_ws);
  spmm_topk_kernel<<<BATCH / BT, 1024, 0, stream>>>(x, (const int4*)d_ws, out);
}

// Round 6
// 391.381 us; speedup vs baseline: 1.2517x; 1.2517x over previous
//
#include <hip/hip_runtime.h>
#include <hip/hip_fp16.h>
#include <stdint.h>

#define IN    4096
#define OUT   4096
#define BATCH 8192
#define TK    64
#define BT    8     // batch rows per block in the spmm kernel

typedef float  fx4 __attribute__((ext_vector_type(4)));   // native vector for nt-load

// ---------------------------------------------------------------------------
// Kernel 1: ONE WAVE PER ROW top-K.
//  - 16-round MSB-greedy threshold search on the TOP 16 BITS of the
//    order-preserving key transform (key>>16 >= P  <=>  key >= P<<16).
//  - exact tie resolution inside the 16-bit boundary bucket via 28-round
//    ballot search over packed = (low16<<12) | (4095-idx); inverted idx
//    prefers SMALLER index, matching jax.lax.top_k tie order.
//  - emission positions bank-quad scheduled: pos k gets idx with
//    idx&7 == (row+k)&7 where possible (spmm step-k gather spreads 64 lanes
//    over the 8 LDS bank quads).
//  - wt payload: {idx, fp16(val) duplicated in both halves} feeding
//    v_pk_fma_f16 in spmm with zero conversion.
// ---------------------------------------------------------------------------
__global__ __launch_bounds__(256)
void topk_build_kernel(const float* __restrict__ pre_w,
                       const float* __restrict__ sign_m,
                       int2* __restrict__ wt) {
  __shared__ int selbuf[4][TK];
  __shared__ uint32_t bucket[4][128];

  const int wid  = threadIdx.x >> 6;
  const int lane = threadIdx.x & 63;
  const int row  = blockIdx.x * 4 + wid;
  const float* pw = pre_w + (size_t)row * IN;
  const uint64_t lt = (1ull << lane) - 1ull;

  // load 64 keys per lane; keys[j*4+c] <-> global index j*256 + lane*4 + c
  uint32_t keys[64];
  #pragma unroll
  for (int j = 0; j < 16; ++j) {
    const float4 v = *(const float4*)(pw + j * 256 + lane * 4);
    const uint32_t u0 = __float_as_uint(v.x);
    const uint32_t u1 = __float_as_uint(v.y);
    const uint32_t u2 = __float_as_uint(v.z);
    const uint32_t u3 = __float_as_uint(v.w);
    keys[j * 4 + 0] = (u0 & 0x80000000u) ? ~u0 : (u0 | 0x80000000u);
    keys[j * 4 + 1] = (u1 & 0x80000000u) ? ~u1 : (u1 | 0x80000000u);
    keys[j * 4 + 2] = (u2 & 0x80000000u) ? ~u2 : (u2 | 0x80000000u);
    keys[j * 4 + 3] = (u3 & 0x80000000u) ? ~u3 : (u3 | 0x80000000u);
  }

  // ---- phase A: largest 16-bit prefix P with count(key>>16 >= P) >= TK ----
  uint32_t curH = 0u;
  for (int b = 15; b >= 0; --b) {
    const uint32_t candF = (curH | (1u << b)) << 16;
    int c = 0;
    #pragma unroll
    for (int i = 0; i < 64; ++i) c += (keys[i] >= candF) ? 1 : 0;
    #pragma unroll
    for (int off = 32; off > 0; off >>= 1) c += __shfl_xor(c, off, 64);
    if (c >= TK) curH |= (1u << b);
  }

  // strict-above count ng and bucket count nb (packed 16|16 single reduce)
  int pk = 0;
  #pragma unroll
  for (int i = 0; i < 64; ++i) {
    const uint32_t kh = keys[i] >> 16;
    pk += (kh > curH) ? 1 : 0;
    pk += (kh == curH) ? (1 << 16) : 0;
  }
  #pragma unroll
  for (int off = 32; off > 0; off >>= 1) pk += __shfl_xor(pk, off, 64);
  const int ng = pk & 0xFFFF;
  const int nb = pk >> 16;
  const int m  = TK - ng;            // 1..TK entries to take from the bucket

  // ---- phase B: collect bucket, find m-th largest packed value ----
  {
    int base = 0;
    #pragma unroll
    for (int i = 0; i < 64; ++i) {
      const bool hit = (keys[i] >> 16) == curH;
      const uint64_t msk = __ballot(hit);
      if (hit) {
        const int p = base + (int)__popcll(msk & lt);
        const int idx = (i >> 2) * 256 + lane * 4 + (i & 3);
        if (p < 128) bucket[wid][p] = ((keys[i] & 0xFFFFu) << 12) | (uint32_t)(4095 - idx);
      }
      base += (int)__popcll(msk);
    }
  }
  __syncthreads();

  uint32_t curB = 0u;
  if (nb != m) {                      // nb==m -> take the whole bucket, skip search
    const uint32_t v0 = (lane      < nb) ? bucket[wid][lane]      : 0u;
    const uint32_t v1 = (lane + 64 < nb) ? bucket[wid][lane + 64] : 0u;
    for (int b = 27; b >= 0; --b) {
      const uint32_t cand = curB | (1u << b);
      const int c = (int)__popcll(__ballot(v0 >= cand)) + (int)__popcll(__ballot(v1 >= cand));
      if (c >= m) curB = cand;
    }
  }

  // ---- emission: compact the exact selection set into selbuf ----
  {
    int base = 0;
    #pragma unroll
    for (int i = 0; i < 64; ++i) {
      const uint32_t kh = keys[i] >> 16;
      const int idx = (i >> 2) * 256 + lane * 4 + (i & 3);
      const uint32_t packed = ((keys[i] & 0xFFFFu) << 12) | (uint32_t)(4095 - idx);
      const bool sel = (kh > curH) || ((kh == curH) && (packed >= curB));
      const uint64_t msk = __ballot(sel);
      if (sel) selbuf[wid][base + (int)__popcll(msk & lt)] = idx;
      base += (int)__popcll(msk);
    }
  }
  __syncthreads();

  // ---- bank-quad position assignment (ballot-based, rotated levels) ----
  const int myidx = selbuf[wid][lane];   // exactly TK=64 entries = 64 lanes
  const int q = myidx & 7;               // LDS bank quad of this index
  const int s = (row >> 3) & 7;          // per-row level rotation

  uint64_t mymask = 0ull;
  int cq[8];
  #pragma unroll
  for (int j = 0; j < 8; ++j) {
    const uint64_t mm = __ballot(q == j);
    cq[j] = (int)__popcll(mm);
    if (q == j) mymask = mm;
  }
  const int r = (int)__popcll(mymask & lt);  // rank within quad class

  int pos;
  if (r < 8) {
    pos = ((q - row) & 7) + 8 * ((r + s) & 7);
  } else {
    int R = r - 8;
    #pragma unroll
    for (int j = 0; j < 8; ++j) if (j < q && cq[j] > 8) R += cq[j] - 8;
    int acc = 0; pos = -1;
    #pragma unroll
    for (int cc = 0; cc < 8; ++cc) {
      int g = 0;
      #pragma unroll
      for (int j = 0; j < 8; ++j)
        if (((row + cc) & 7) == j) g = (cq[j] < 8) ? cq[j] : 8;
      const int f = 8 - g;
      if (pos < 0 && R < acc + f) pos = cc + 8 * ((g + (R - acc) + s) & 7);
      acc += f;
    }
  }

  const float v = expf(pw[myidx]) * sign_m[(size_t)row * IN + myidx];
  const uint32_t hb = (uint32_t)__half_as_ushort(__float2half_rn(v));
  int2* dst = wt + (((size_t)(pos >> 1) * OUT + row) * 2 + (pos & 1));
  *dst = make_int2(myidx, (int)(hb | (hb << 16)));
}

// ---------------------------------------------------------------------------
// Kernel 2: sparse matmul. Block = BT batch rows x all OUT outputs.
// x staged in LDS fp16 transposed (row i = 8 batch vals = 16 B).
// Per (o,k): 1x ds_read_b128 gather + 4x v_pk_fma_f16. Fully-unrolled k-loop
// with explicit 2x int4 register prefetch (round-2 skeleton: overlap wt L2
// latency with current group's gather+FMA). fp16 accumulation in 4 static
// chains of 16, combined in fp32. Plain out stores (L2 write-back);
// nt x-loads keep the one-shot x stream from evicting the hot wt lines.
// ---------------------------------------------------------------------------
__device__ __forceinline__ uint32_t pack_f16x2(float a, float b) {
  const uint32_t lo = __half_as_ushort(__float2half(a));
  const uint32_t hi = __half_as_ushort(__float2half(b));
  return lo | (hi << 16);
}

__global__ __launch_bounds__(1024, 8)
void spmm_topk_kernel(const float* __restrict__ x,
                      const int4* __restrict__ wt4,
                      float* __restrict__ out) {
  __shared__ uint16_t ldsx[IN * BT];   // 64 KB: row i at byte offset i*16

  const int tid = threadIdx.x;
  const int b0 = blockIdx.x * BT;

  // ---- stage: 8 rows of x -> LDS fp16 transposed ----
  {
    const int i4 = tid * 4;
    float c[4][BT];
    #pragma unroll
    for (int j = 0; j < BT; ++j) {
      const fx4* src = (const fx4*)(x + (size_t)(b0 + j) * IN + i4);
      const fx4 v = __builtin_nontemporal_load(src);
      c[0][j] = v.x; c[1][j] = v.y; c[2][j] = v.z; c[3][j] = v.w;
    }
    #pragma unroll
    for (int rr = 0; rr < 4; ++rr) {
      uint4 pkv;
      pkv.x = pack_f16x2(c[rr][0], c[rr][1]);
      pkv.y = pack_f16x2(c[rr][2], c[rr][3]);
      pkv.z = pack_f16x2(c[rr][4], c[rr][5]);
      pkv.w = pack_f16x2(c[rr][6], c[rr][7]);
      *(uint4*)(&ldsx[(i4 + rr) * BT]) = pkv;
    }
  }
  __syncthreads();

  const int wave = tid >> 6;
  const int lane = tid & 63;

  for (int g = wave; g < (OUT / 64); g += 16) {   // 4 groups per wave
    const int o = g * 64 + lane;
    const int4* wq = wt4 + o;                     // element k2 at wq[k2*OUT]

    __half2 acc0[4], acc1[4], acc2[4], acc3[4];   // 4 chains x 4 batch-pairs
    #pragma unroll
    for (int j = 0; j < 4; ++j) {
      acc0[j] = __float2half2_rn(0.f);
      acc1[j] = __float2half2_rn(0.f);
      acc2[j] = __float2half2_rn(0.f);
      acc3[j] = __float2half2_rn(0.f);
    }

    int4 p0 = wq[0];
    int4 p1 = wq[OUT];

    #pragma unroll
    for (int k2 = 0; k2 < (TK / 2); k2 += 2) {    // 4 k-entries per iter
      int4 n0, n1;
      if (k2 + 2 < (TK / 2)) {                    // prefetch next group (static)
        n0 = wq[(size_t)(k2 + 2) * OUT];
        n1 = wq[(size_t)(k2 + 3) * OUT];
      }
      const uint4 xa = *(const uint4*)(&ldsx[p0.x * BT]);   // quad-scheduled gathers
      const uint4 xb = *(const uint4*)(&ldsx[p0.z * BT]);
      const uint4 xc = *(const uint4*)(&ldsx[p1.x * BT]);
      const uint4 xd = *(const uint4*)(&ldsx[p1.z * BT]);
      const __half2 va = *(const __half2*)&p0.y;
      const __half2 vb = *(const __half2*)&p0.w;
      const __half2 vc = *(const __half2*)&p1.y;
      const __half2 vd = *(const __half2*)&p1.w;
      const __half2* ha = (const __half2*)&xa;
      const __half2* hb = (const __half2*)&xb;
      const __half2* hc = (const __half2*)&xc;
      const __half2* hd = (const __half2*)&xd;
      #pragma unroll
      for (int j = 0; j < 4; ++j) {
        acc0[j] = __hfma2(ha[j], va, acc0[j]);
        acc1[j] = __hfma2(hb[j], vb, acc1[j]);
        acc2[j] = __hfma2(hc[j], vc, acc2[j]);
        acc3[j] = __hfma2(hd[j], vd, acc3[j]);
      }
      if (k2 + 2 < (TK / 2)) { p0 = n0; p1 = n1; }
    }

    // epilogue: combine 4 fp16 chains in fp32, plain stores
    float* op = out + (size_t)b0 * OUT + o;
    #pragma unroll
    for (int j = 0; j < 4; ++j) {
      const float lo = (__low2float(acc0[j])  + __low2float(acc1[j])) +
                       (__low2float(acc2[j])  + __low2float(acc3[j]));
      const float hi = (__high2float(acc0[j]) + __high2float(acc1[j])) +
                       (__high2float(acc2[j]) + __high2float(acc3[j]));
      op[(size_t)(2 * j) * OUT]     = lo;
      op[(size_t)(2 * j + 1) * OUT] = hi;
    }
  }
}

// ---------------------------------------------------------------------------
extern "C" void kernel_launch(void* const* d_in, const int* in_sizes, int n_in,
                              void* d_out, int out_size, void* d_ws, size_t ws_size,
                              hipStream_t stream) {
  const float* x      = (const float*)d_in[0];
  const float* pre_w  = (const float*)d_in[1];
  const float* sign_m = (const float*)d_in[2];
  float* out = (float*)d_out;

  topk_build_kernel<<<OUT / 4, 256, 0, stream>>>(pre_w, sign_m, (int2*)d_ws);
  spmm_topk_kernel<<<BATCH / BT, 1024, 0, stream>>>(x, (const int4*)d_ws, out);
}